// Round 4
// baseline (320.897 us; speedup 1.0000x reference)
//
#include <hip/hip_runtime.h>
#include <hip/hip_bf16.h>

#define B_N 4096
#define M_N 16384
#define D_N 512
#define NC_N 100
#define NCP 112
#define BT 32
#define SPLITM 4

typedef float f32x4 __attribute__((ext_vector_type(4)));
typedef short bf16x8 __attribute__((ext_vector_type(8)));

__device__ __forceinline__ unsigned short f2bf(float f) {
  unsigned int u = __float_as_uint(f);
  u += 0x7FFFu + ((u >> 16) & 1u);
  return (unsigned short)(u >> 16);
}

// Convert rows of src (nrows x 512 fp32) to bf16 and compute squared norms.
__global__ void prep_rows(const float* __restrict__ src, unsigned short* __restrict__ dst,
                          float* __restrict__ norms) {
  int row = blockIdx.x * 4 + (threadIdx.x >> 6);
  int lane = threadIdx.x & 63;
  const float4* s = (const float4*)(src + (size_t)row * D_N);
  float4 v0 = s[lane * 2];
  float4 v1 = s[lane * 2 + 1];
  float acc = v0.x * v0.x + v0.y * v0.y + v0.z * v0.z + v0.w * v0.w +
              v1.x * v1.x + v1.y * v1.y + v1.z * v1.z + v1.w * v1.w;
  unsigned int p0 = f2bf(v0.x) | ((unsigned int)f2bf(v0.y) << 16);
  unsigned int p1 = f2bf(v0.z) | ((unsigned int)f2bf(v0.w) << 16);
  unsigned int p2 = f2bf(v1.x) | ((unsigned int)f2bf(v1.y) << 16);
  unsigned int p3 = f2bf(v1.z) | ((unsigned int)f2bf(v1.w) << 16);
  uint4 w4; w4.x = p0; w4.y = p1; w4.z = p2; w4.w = p3;
  *(uint4*)(dst + (size_t)row * D_N + lane * 8) = w4;
  #pragma unroll
  for (int off = 1; off < 64; off <<= 1) acc += __shfl_xor(acc, off);
  if (lane == 0) norms[row] = acc;
}

// C (M x 100 fp32) -> CT (112 x M bf16), rows 100..111 zero.
__global__ void prep_ct(const float* __restrict__ C, unsigned short* __restrict__ CT) {
  int m = blockIdx.x * 256 + threadIdx.x;
  int c = blockIdx.y;
  unsigned short v = 0;
  if (c < NC_N) v = f2bf(C[(size_t)m * NC_N + c]);
  CT[(size_t)c * M_N + m] = v;
}

// Main fused kernel, BT=32 b-tile: LDS ~74.5 KB -> 2 blocks/CU (4 waves/SIMD).
__global__ __launch_bounds__(512, 4)
void fused_main(const unsigned short* __restrict__ Abf,
                const unsigned short* __restrict__ Xbf,
                const unsigned short* __restrict__ CTbf,
                const float* __restrict__ aa, const float* __restrict__ xx,
                float* __restrict__ pacc, float* __restrict__ pden, int splitm) {
  __shared__ unsigned short Xl[BT * 520];        // X tile, padded row stride
  __shared__ union {
    unsigned short Pl[8][BT * 40];               // per-wave P^T tile [b][m], stride 40
    float Cacc[NCP * BT];                        // aliased: used only after main loop
  } sh;
  __shared__ float Cden[BT];

  const int t = threadIdx.x;
  const int w = t >> 6;
  const int l = t & 63;
  const int g = l >> 4;
  const int r16 = l & 15;
  const int bbase = blockIdx.x * BT;
  const int sidx = blockIdx.y;

  // stage X tile (32 x 512 bf16) into LDS
  #pragma unroll
  for (int i = 0; i < 2048 / 512; ++i) {
    int q = t + 512 * i;
    int row = q >> 6, col8 = q & 63;
    uint4 v = *(const uint4*)(Xbf + (size_t)(bbase + row) * D_N + col8 * 8);
    *(uint4*)(&Xl[row * 520 + col8 * 8]) = v;
  }
  __syncthreads();

  float xxv[2];
  #pragma unroll
  for (int bs = 0; bs < 2; ++bs) xxv[bs] = xx[bbase + bs * 16 + r16];

  f32x4 oacc[7][2];
  #pragma unroll
  for (int ct = 0; ct < 7; ++ct)
    #pragma unroll
    for (int bs = 0; bs < 2; ++bs) oacc[ct][bs] = (f32x4){0.f, 0.f, 0.f, 0.f};
  float den[2] = {0.f, 0.f};

  unsigned short* Plw = &sh.Pl[w][0];

  for (int T = sidx + splitm * w; T < M_N / 32; T += splitm * 8) {
    int m0 = T * 32;
    f32x4 sacc[2][2];
    #pragma unroll
    for (int ms = 0; ms < 2; ++ms)
      #pragma unroll
      for (int bs = 0; bs < 2; ++bs) sacc[ms][bs] = (f32x4){0.f, 0.f, 0.f, 0.f};

    #pragma unroll 4
    for (int ki = 0; ki < 16; ++ki) {
      int k0 = ki * 32 + 8 * g;
      bf16x8 a0 = *(const bf16x8*)(Abf + (size_t)(m0 + r16) * D_N + k0);
      bf16x8 a1 = *(const bf16x8*)(Abf + (size_t)(m0 + 16 + r16) * D_N + k0);
      #pragma unroll
      for (int bs = 0; bs < 2; ++bs) {
        bf16x8 xf = *(const bf16x8*)(&Xl[(bs * 16 + r16) * 520 + k0]);
        sacc[0][bs] = __builtin_amdgcn_mfma_f32_16x16x32_bf16(a0, xf, sacc[0][bs], 0, 0, 0);
        sacc[1][bs] = __builtin_amdgcn_mfma_f32_16x16x32_bf16(a1, xf, sacc[1][bs], 0, 0, 0);
      }
    }

    // epilogue: d2 -> dist -> p = exp(-dist/4); write P^T tile to per-wave LDS
    #pragma unroll
    for (int ms = 0; ms < 2; ++ms) {
      f32x4 aa4 = *(const f32x4*)(aa + m0 + ms * 16 + 4 * g);
      #pragma unroll
      for (int bs = 0; bs < 2; ++bs) {
        f32x4 s4 = sacc[ms][bs];
        float e[4];
        #pragma unroll
        for (int r = 0; r < 4; ++r) {
          float d2 = aa4[r] + xxv[bs] - 2.0f * s4[r];
          float dist = __builtin_amdgcn_sqrtf(fmaxf(d2, 0.0f));
          e[r] = exp2f(-0.36067376022224085f * dist);  // exp(-dist/4)
        }
        den[bs] += (e[0] + e[1]) + (e[2] + e[3]);
        __hip_bfloat162 h01 = __float22bfloat162_rn(make_float2(e[0], e[1]));
        __hip_bfloat162 h23 = __float22bfloat162_rn(make_float2(e[2], e[3]));
        uint2 pk;
        pk.x = *reinterpret_cast<unsigned*>(&h01);
        pk.y = *reinterpret_cast<unsigned*>(&h23);
        *(uint2*)(&Plw[(bs * 16 + r16) * 40 + ms * 16 + 4 * g]) = pk;
      }
    }

    // out^T += C^T * P  (K = 32 = this m-tile)
    bf16x8 pf[2];
    #pragma unroll
    for (int bs = 0; bs < 2; ++bs)
      pf[bs] = *(const bf16x8*)(&Plw[(bs * 16 + r16) * 40 + 8 * g]);
    #pragma unroll
    for (int ct = 0; ct < 7; ++ct) {
      bf16x8 cf = *(const bf16x8*)(CTbf + (size_t)(ct * 16 + r16) * M_N + m0 + 8 * g);
      #pragma unroll
      for (int bs = 0; bs < 2; ++bs)
        oacc[ct][bs] = __builtin_amdgcn_mfma_f32_16x16x32_bf16(cf, pf[bs], oacc[ct][bs], 0, 0, 0);
    }
  }

  // reduce den across the 4 lane-groups (column sums)
  #pragma unroll
  for (int bs = 0; bs < 2; ++bs) {
    float d = den[bs];
    d += __shfl_xor(d, 16);
    d += __shfl_xor(d, 32);
    den[bs] = d;
  }

  // combine the 8 waves' partials in LDS (Cacc aliases Pl — Pl dead now)
  __syncthreads();
  for (int i = t; i < NCP * BT; i += 512) sh.Cacc[i] = 0.f;
  if (t < BT) Cden[t] = 0.f;
  __syncthreads();

  for (int ww = 0; ww < 8; ++ww) {
    if (w == ww) {
      #pragma unroll
      for (int ct = 0; ct < 7; ++ct)
        #pragma unroll
        for (int bs = 0; bs < 2; ++bs)
          #pragma unroll
          for (int r = 0; r < 4; ++r)
            sh.Cacc[(ct * 16 + 4 * g + r) * BT + bs * 16 + r16] += oacc[ct][bs][r];
      if (g == 0)
        #pragma unroll
        for (int bs = 0; bs < 2; ++bs) Cden[bs * 16 + r16] += den[bs];
    }
    __syncthreads();
  }

  // write partial accumulators: pacc[s][c][b], pden[s][b]
  float* paccS = pacc + (size_t)sidx * NCP * B_N;
  for (int i = t; i < NCP * BT; i += 512) {
    int c = i >> 5, bl = i & (BT - 1);
    paccS[(size_t)c * B_N + bbase + bl] = sh.Cacc[i];
  }
  if (t < BT) pden[sidx * B_N + bbase + t] = Cden[t];
}

// Finalize: 256 blocks, each owns 16 b's; tile (16c x 16b) threads.
#define FB 16
__global__ __launch_bounds__(256)
void finalize(const float* __restrict__ pacc, const float* __restrict__ pden,
              float* __restrict__ out, int splitm) {
  __shared__ float tile[NC_N][FB];
  __shared__ float dinv[FB];
  const int t = threadIdx.x;
  const int b0 = blockIdx.x * FB;
  const int tb = t & 15;
  const int tc = t >> 4;

  if (t < FB) {
    float dn = 0.f;
    for (int s = 0; s < splitm; ++s) dn += pden[s * B_N + b0 + t];
    dinv[t] = 1.0f / dn;
  }

  for (int c = tc; c < NC_N; c += 16) {
    float a = 0.f;
    for (int s = 0; s < splitm; ++s)
      a += pacc[((size_t)s * NCP + c) * B_N + b0 + tb];
    tile[c][tb] = a;
  }
  __syncthreads();

  for (int i = t; i < FB * NC_N; i += 256) {
    int b = i / NC_N, c = i - b * NC_N;
    out[(size_t)(b0 + b) * NC_N + c] = tile[c][b] * dinv[b];
  }
}

extern "C" void kernel_launch(void* const* d_in, const int* in_sizes, int n_in,
                              void* d_out, int out_size, void* d_ws, size_t ws_size,
                              hipStream_t stream) {
  const float* X = (const float*)d_in[0];
  const float* A = (const float*)d_in[1];
  const float* C = (const float*)d_in[2];
  float* out = (float*)d_out;

  char* ws = (char*)d_ws;
  size_t off = 0;
  auto alloc = [&](size_t bytes) -> void* {
    void* p = ws + off;
    off += (bytes + 255) & ~(size_t)255;
    return p;
  };
  unsigned short* Abf = (unsigned short*)alloc((size_t)M_N * D_N * 2);
  unsigned short* Xbf = (unsigned short*)alloc((size_t)B_N * D_N * 2);
  unsigned short* CT  = (unsigned short*)alloc((size_t)NCP * M_N * 2);
  float* aa = (float*)alloc((size_t)M_N * 4);
  float* xx = (float*)alloc((size_t)B_N * 4);

  size_t per_split = ((size_t)NCP * B_N * 4 + 256) + ((size_t)B_N * 4 + 256);
  int splitm = SPLITM;
  while (splitm > 1 && off + (size_t)splitm * per_split > ws_size) splitm >>= 1;
  float* pacc = (float*)alloc((size_t)splitm * NCP * B_N * 4);
  float* pden = (float*)alloc((size_t)splitm * B_N * 4);

  prep_rows<<<M_N / 4, 256, 0, stream>>>(A, Abf, aa);
  prep_rows<<<B_N / 4, 256, 0, stream>>>(X, Xbf, xx);
  prep_ct<<<dim3(M_N / 256, NCP), 256, 0, stream>>>(C, CT);
  fused_main<<<dim3(B_N / BT, splitm), 512, 0, stream>>>(Abf, Xbf, CT, aa, xx, pacc, pden, splitm);
  finalize<<<B_N / FB, 256, 0, stream>>>(pacc, pden, out, splitm);
}

// Round 5
// 159.804 us; speedup vs baseline: 2.0081x; 2.0081x over previous
//
#include <hip/hip_runtime.h>
#include <hip/hip_bf16.h>

#define B_N 4096
#define M_N 16384
#define D_N 512
#define NC_N 100
#define NCP 112
#define BT 64
#define SPLITM 4

typedef float f32x4 __attribute__((ext_vector_type(4)));
typedef short bf16x8 __attribute__((ext_vector_type(8)));

__device__ __forceinline__ unsigned short f2bf(float f) {
  unsigned int u = __float_as_uint(f);
  u += 0x7FFFu + ((u >> 16) & 1u);
  return (unsigned short)(u >> 16);
}

// X: rows -> bf16 (plain row-major) + squared norms.
__global__ void prep_rows(const float* __restrict__ src, unsigned short* __restrict__ dst,
                          float* __restrict__ norms) {
  int row = blockIdx.x * 4 + (threadIdx.x >> 6);
  int lane = threadIdx.x & 63;
  const float4* s = (const float4*)(src + (size_t)row * D_N);
  float4 v0 = s[lane * 2];
  float4 v1 = s[lane * 2 + 1];
  float acc = v0.x * v0.x + v0.y * v0.y + v0.z * v0.z + v0.w * v0.w +
              v1.x * v1.x + v1.y * v1.y + v1.z * v1.z + v1.w * v1.w;
  uint4 w4;
  w4.x = f2bf(v0.x) | ((unsigned int)f2bf(v0.y) << 16);
  w4.y = f2bf(v0.z) | ((unsigned int)f2bf(v0.w) << 16);
  w4.z = f2bf(v1.x) | ((unsigned int)f2bf(v1.y) << 16);
  w4.w = f2bf(v1.z) | ((unsigned int)f2bf(v1.w) << 16);
  *(uint4*)(dst + (size_t)row * D_N + lane * 8) = w4;
  #pragma unroll
  for (int off = 1; off < 64; off <<= 1) acc += __shfl_xor(acc, off);
  if (lane == 0) norms[row] = acc;
}

// A: squared norms only (coalesced read, no store).
__global__ void prep_norms(const float* __restrict__ src, float* __restrict__ norms) {
  int row = blockIdx.x * 4 + (threadIdx.x >> 6);
  int lane = threadIdx.x & 63;
  const float4* s = (const float4*)(src + (size_t)row * D_N);
  float4 v0 = s[lane * 2];
  float4 v1 = s[lane * 2 + 1];
  float acc = v0.x * v0.x + v0.y * v0.y + v0.z * v0.z + v0.w * v0.w +
              v1.x * v1.x + v1.y * v1.y + v1.z * v1.z + v1.w * v1.w;
  #pragma unroll
  for (int off = 1; off < 64; off <<= 1) acc += __shfl_xor(acc, off);
  if (lane == 0) norms[row] = acc;
}

// A fp32 -> A2 bf16 in MFMA-fragment order:
// chunk(T,ki,half) of 64 lanes x 8 elems; lane l=(g*16+r16) holds
// A[T*32 + half*16 + r16][ki*32 + g*8 .. +7].  Hot-loop load = base + l*16B.
__global__ void prep_a2(const float* __restrict__ A, unsigned short* __restrict__ A2) {
  int idx = blockIdx.x * 256 + threadIdx.x;       // 2^20 total
  int r16 = idx & 15;
  int g = (idx >> 4) & 3;
  int half = (idx >> 6) & 1;
  int ki = (idx >> 7) & 15;
  int T = idx >> 11;
  int row = T * 32 + half * 16 + r16;
  int col = ki * 32 + g * 8;
  const float4* s = (const float4*)(A + (size_t)row * D_N + col);
  float4 v0 = s[0];
  float4 v1 = s[1];
  uint4 w4;
  w4.x = f2bf(v0.x) | ((unsigned int)f2bf(v0.y) << 16);
  w4.y = f2bf(v0.z) | ((unsigned int)f2bf(v0.w) << 16);
  w4.z = f2bf(v1.x) | ((unsigned int)f2bf(v1.y) << 16);
  w4.w = f2bf(v1.z) | ((unsigned int)f2bf(v1.w) << 16);
  *(uint4*)(A2 + (size_t)idx * 8) = w4;
}

// C fp32 (M x 100) -> CT2 bf16 fragment order: chunk(T,ct) of 64 lanes x 8;
// lane l=(g*16+r16) holds C^T[ct*16+r16][T*32 + g*8 .. +7] (c>=100 -> 0).
__global__ void prep_ct2(const float* __restrict__ C, unsigned short* __restrict__ CT2) {
  int idx = blockIdx.x * 256 + threadIdx.x;       // 512*7*64 total
  int r16 = idx & 15;
  int g = (idx >> 4) & 3;
  int rest = idx >> 6;
  int ct = rest % 7;
  int T = rest / 7;
  int c = ct * 16 + r16;
  int m0 = T * 32 + g * 8;
  unsigned short e[8];
  #pragma unroll
  for (int j = 0; j < 8; ++j)
    e[j] = (c < NC_N) ? f2bf(C[(size_t)(m0 + j) * NC_N + c]) : (unsigned short)0;
  uint4 w4;
  w4.x = e[0] | ((unsigned int)e[1] << 16);
  w4.y = e[2] | ((unsigned int)e[3] << 16);
  w4.z = e[4] | ((unsigned int)e[5] << 16);
  w4.w = e[6] | ((unsigned int)e[7] << 16);
  *(uint4*)(CT2 + (size_t)idx * 8) = w4;
}

// Main fused kernel. All global loads coalesced (fragment-ordered A2/CT2);
// X tile in LDS with XOR slot swizzle (slot ^= row&7) -> 2-way max conflicts.
__global__ __launch_bounds__(512, 2)
void fused_main(const unsigned short* __restrict__ A2,
                const unsigned short* __restrict__ Xbf,
                const unsigned short* __restrict__ CT2,
                const float* __restrict__ aa, const float* __restrict__ xx,
                float* __restrict__ pacc, float* __restrict__ pden, int splitm) {
  __shared__ unsigned short Xl[BT * 512];          // 64 KB, swizzled 16B slots
  __shared__ union {
    unsigned short Pl[8][BT * 40];                 // per-wave P^T tile, stride 40
    float Cacc[NCP * BT];                          // aliased after main loop
  } sh;
  __shared__ float Cden[BT];

  const int t = threadIdx.x;
  const int w = t >> 6;
  const int l = t & 63;
  const int g = l >> 4;
  const int r16 = l & 15;
  const int bbase = blockIdx.x * BT;
  const int sidx = blockIdx.y;

  // stage X tile (64 x 512 bf16), swizzled: slot' = slot ^ (row & 7)
  #pragma unroll
  for (int i = 0; i < 8; ++i) {
    int q = t + 512 * i;
    int row = q >> 6, s = q & 63;
    uint4 v = *(const uint4*)(Xbf + (size_t)(bbase + row) * D_N + s * 8);
    *(uint4*)(&Xl[row * 512 + (s ^ (row & 7)) * 8]) = v;
  }
  __syncthreads();

  float xxv[4];
  #pragma unroll
  for (int bs = 0; bs < 4; ++bs) xxv[bs] = xx[bbase + bs * 16 + r16];

  f32x4 oacc[7][4];
  #pragma unroll
  for (int ct = 0; ct < 7; ++ct)
    #pragma unroll
    for (int bs = 0; bs < 4; ++bs) oacc[ct][bs] = (f32x4){0.f, 0.f, 0.f, 0.f};
  float den[4] = {0.f, 0.f, 0.f, 0.f};

  unsigned short* Plw = &sh.Pl[w][0];
  const bf16x8* Ab = (const bf16x8*)A2;
  const bf16x8* Cb = (const bf16x8*)CT2;
  const int swz = r16 & 7;

  for (int T = sidx + splitm * w; T < M_N / 32; T += splitm * 8) {
    const int m0 = T * 32;
    f32x4 sacc[2][4];
    #pragma unroll
    for (int ms = 0; ms < 2; ++ms)
      #pragma unroll
      for (int bs = 0; bs < 4; ++bs) sacc[ms][bs] = (f32x4){0.f, 0.f, 0.f, 0.f};

    // hoisted coalesced CT2 loads (1 KB per instruction)
    bf16x8 cf[7];
    #pragma unroll
    for (int ct = 0; ct < 7; ++ct)
      cf[ct] = Cb[(size_t)(T * 7 + ct) * 64 + l];

    #pragma unroll 4
    for (int ki = 0; ki < 16; ++ki) {
      bf16x8 a0 = Ab[(size_t)((T * 16 + ki) * 2 + 0) * 64 + l];
      bf16x8 a1 = Ab[(size_t)((T * 16 + ki) * 2 + 1) * 64 + l];
      #pragma unroll
      for (int bs = 0; bs < 4; ++bs) {
        bf16x8 xf = *(const bf16x8*)(&Xl[(bs * 16 + r16) * 512 + ((4 * ki + g) ^ swz) * 8]);
        sacc[0][bs] = __builtin_amdgcn_mfma_f32_16x16x32_bf16(a0, xf, sacc[0][bs], 0, 0, 0);
        sacc[1][bs] = __builtin_amdgcn_mfma_f32_16x16x32_bf16(a1, xf, sacc[1][bs], 0, 0, 0);
      }
    }

    // epilogue: d2 -> dist -> p = exp(-dist/4); write P^T tile to per-wave LDS
    #pragma unroll
    for (int ms = 0; ms < 2; ++ms) {
      f32x4 aa4 = *(const f32x4*)(aa + m0 + ms * 16 + 4 * g);
      #pragma unroll
      for (int bs = 0; bs < 4; ++bs) {
        f32x4 s4 = sacc[ms][bs];
        float e[4];
        #pragma unroll
        for (int r = 0; r < 4; ++r) {
          float d2 = aa4[r] + xxv[bs] - 2.0f * s4[r];
          float dist = __builtin_amdgcn_sqrtf(fmaxf(d2, 0.0f));
          e[r] = exp2f(-0.36067376022224085f * dist);  // exp(-dist/4)
        }
        den[bs] += (e[0] + e[1]) + (e[2] + e[3]);
        __hip_bfloat162 h01 = __float22bfloat162_rn(make_float2(e[0], e[1]));
        __hip_bfloat162 h23 = __float22bfloat162_rn(make_float2(e[2], e[3]));
        uint2 pk;
        pk.x = *reinterpret_cast<unsigned*>(&h01);
        pk.y = *reinterpret_cast<unsigned*>(&h23);
        *(uint2*)(&Plw[(bs * 16 + r16) * 40 + ms * 16 + 4 * g]) = pk;
      }
    }

    // out^T += C^T * P  (K = 32 = this m-tile)
    bf16x8 pf[4];
    #pragma unroll
    for (int bs = 0; bs < 4; ++bs)
      pf[bs] = *(const bf16x8*)(&Plw[(bs * 16 + r16) * 40 + 8 * g]);
    #pragma unroll
    for (int ct = 0; ct < 7; ++ct)
      #pragma unroll
      for (int bs = 0; bs < 4; ++bs)
        oacc[ct][bs] = __builtin_amdgcn_mfma_f32_16x16x32_bf16(cf[ct], pf[bs], oacc[ct][bs], 0, 0, 0);
  }

  // reduce den across the 4 lane-groups (column sums)
  #pragma unroll
  for (int bs = 0; bs < 4; ++bs) {
    float d = den[bs];
    d += __shfl_xor(d, 16);
    d += __shfl_xor(d, 32);
    den[bs] = d;
  }

  // combine the 8 waves' partials in LDS (Cacc aliases Pl — Pl dead now)
  __syncthreads();
  for (int i = t; i < NCP * BT; i += 512) sh.Cacc[i] = 0.f;
  if (t < BT) Cden[t] = 0.f;
  __syncthreads();

  for (int ww = 0; ww < 8; ++ww) {
    if (w == ww) {
      #pragma unroll
      for (int ct = 0; ct < 7; ++ct)
        #pragma unroll
        for (int bs = 0; bs < 4; ++bs)
          #pragma unroll
          for (int r = 0; r < 4; ++r)
            sh.Cacc[(ct * 16 + 4 * g + r) * BT + bs * 16 + r16] += oacc[ct][bs][r];
      if (g == 0)
        #pragma unroll
        for (int bs = 0; bs < 4; ++bs) Cden[bs * 16 + r16] += den[bs];
    }
    __syncthreads();
  }

  // write partial accumulators: pacc[s][c][b], pden[s][b]
  float* paccS = pacc + (size_t)sidx * NCP * B_N;
  for (int i = t; i < NCP * BT; i += 512) {
    int c = i >> 6, bl = i & (BT - 1);
    paccS[(size_t)c * B_N + bbase + bl] = sh.Cacc[i];
  }
  if (t < BT) pden[sidx * B_N + bbase + t] = Cden[t];
}

// Finalize: 256 blocks, each owns 16 b's; tile (16c x 16b) threads.
#define FB 16
__global__ __launch_bounds__(256)
void finalize(const float* __restrict__ pacc, const float* __restrict__ pden,
              float* __restrict__ out, int splitm) {
  __shared__ float tile[NC_N][FB];
  __shared__ float dinv[FB];
  const int t = threadIdx.x;
  const int b0 = blockIdx.x * FB;
  const int tb = t & 15;
  const int tc = t >> 4;

  if (t < FB) {
    float dn = 0.f;
    for (int s = 0; s < splitm; ++s) dn += pden[s * B_N + b0 + t];
    dinv[t] = 1.0f / dn;
  }

  for (int c = tc; c < NC_N; c += 16) {
    float a = 0.f;
    for (int s = 0; s < splitm; ++s)
      a += pacc[((size_t)s * NCP + c) * B_N + b0 + tb];
    tile[c][tb] = a;
  }
  __syncthreads();

  for (int i = t; i < FB * NC_N; i += 256) {
    int b = i / NC_N, c = i - b * NC_N;
    out[(size_t)(b0 + b) * NC_N + c] = tile[c][b] * dinv[b];
  }
}

extern "C" void kernel_launch(void* const* d_in, const int* in_sizes, int n_in,
                              void* d_out, int out_size, void* d_ws, size_t ws_size,
                              hipStream_t stream) {
  const float* X = (const float*)d_in[0];
  const float* A = (const float*)d_in[1];
  const float* C = (const float*)d_in[2];
  float* out = (float*)d_out;

  char* ws = (char*)d_ws;
  size_t off = 0;
  auto alloc = [&](size_t bytes) -> void* {
    void* p = ws + off;
    off += (bytes + 255) & ~(size_t)255;
    return p;
  };
  unsigned short* A2  = (unsigned short*)alloc((size_t)M_N * D_N * 2);
  unsigned short* Xbf = (unsigned short*)alloc((size_t)B_N * D_N * 2);
  unsigned short* CT2 = (unsigned short*)alloc((size_t)NCP * M_N * 2);
  float* aa = (float*)alloc((size_t)M_N * 4);
  float* xx = (float*)alloc((size_t)B_N * 4);

  size_t per_split = ((size_t)NCP * B_N * 4 + 256) + ((size_t)B_N * 4 + 256);
  int splitm = SPLITM;
  while (splitm > 1 && off + (size_t)splitm * per_split > ws_size) splitm >>= 1;
  float* pacc = (float*)alloc((size_t)splitm * NCP * B_N * 4);
  float* pden = (float*)alloc((size_t)splitm * B_N * 4);

  prep_rows<<<B_N / 4, 256, 0, stream>>>(X, Xbf, xx);
  prep_norms<<<M_N / 4, 256, 0, stream>>>(A, aa);
  prep_a2<<<(M_N * D_N / 8) / 256, 256, 0, stream>>>(A, A2);
  prep_ct2<<<(512 * 7 * 64) / 256, 256, 0, stream>>>(C, CT2);
  fused_main<<<dim3(B_N / BT, splitm), 512, 0, stream>>>(A2, Xbf, CT2, aa, xx, pacc, pden, splitm);
  finalize<<<B_N / FB, 256, 0, stream>>>(pacc, pden, out, splitm);
}